// Round 19
// baseline (108.367 us; speedup 1.0000x reference)
//
#include <hip/hip_runtime.h>

#define B_   16
#define S_   128
#define R_   1024
#define KIN  25
#define H_   128
#define MID  256

typedef _Float16 h8 __attribute__((ext_vector_type(8)));
typedef _Float16 h2 __attribute__((ext_vector_type(2)));
typedef float    f4v __attribute__((ext_vector_type(4)));

__device__ __forceinline__ h2 pk2(float a, float b) {
    auto r = __builtin_amdgcn_cvt_pkrtz(a, b);
    h2 o; o[0] = (_Float16)r[0]; o[1] = (_Float16)r[1]; return o;
}
__device__ __forceinline__ unsigned h2u(h2 v) {
    union { h2 h; unsigned u; } c; c.h = v; return c.u;
}
__device__ __forceinline__ h8 mk8(unsigned a, unsigned b, unsigned c, unsigned d) {
    union { h8 v; unsigned u[4]; } r; r.u[0] = a; r.u[1] = b; r.u[2] = c; r.u[3] = d;
    return r.v;
}

// ---------------------------------------------------------------------------
// prep chain (fp32 until final pack). Wc[k][j], k in ORIGINAL order:
// 0..24 = x, 25..152 = h, 153 = c.  Mh[i][j] = Wc[25+i][j] (h -> h map).
// A-fragment tables MUST be stored transposed: stored[i][k] = M[k][i].
// ---------------------------------------------------------------------------
__global__ void prepA(const float* __restrict__ Wh1, const float* __restrict__ Wh2,
                      const float* __restrict__ Wo1, const float* __restrict__ Wo2,
                      float* __restrict__ Wc, float* __restrict__ wo)
{
    const int k = blockIdx.x, t = threadIdx.x;    // 155 x 128
    if (k < 154) {
        float a = 0.f;
        for (int m = 0; m < MID; ++m) a += Wh1[k * MID + m] * Wh2[m * H_ + t];
        Wc[k * H_ + t] = a;
    } else {
#pragma unroll
        for (int r = 0; r < 2; ++r) {
            int kk = t + r * 128;
            if (kk < 154) {
                float a = 0.f;
                for (int m = 0; m < MID; ++m) a += Wo1[kk * MID + m] * Wo2[m];
                wo[kk] = a;
            }
        }
    }
}
__global__ void prepB(const float* __restrict__ Wc, float* __restrict__ M2)
{   // M2 = Mh^2 (actual orientation)
    const int i = blockIdx.x, t = threadIdx.x;
    float a = 0.f;
    for (int q = 0; q < H_; ++q) a += Wc[(25 + i) * H_ + q] * Wc[(25 + q) * H_ + t];
    M2[i * H_ + t] = a;
}
__global__ void prepC(const float* __restrict__ Wc, const float* __restrict__ M2,
                      float* __restrict__ M3)
{   // M3 = M2 * Mh (actual orientation)
    const int i = blockIdx.x, t = threadIdx.x;
    float a = 0.f;
    for (int q = 0; q < H_; ++q) a += M2[i * H_ + q] * Wc[(25 + q) * H_ + t];
    M3[i * H_ + t] = a;
}
__global__ void prepD(const float* __restrict__ M2, _Float16* __restrict__ W4h)
{   // W4h stored TRANSPOSED for A-frag use: W4h[i][t] = Mh^4[t][i]
    const int i = blockIdx.x, t = threadIdx.x;
    float a = 0.f;
    for (int q = 0; q < H_; ++q) a += M2[t * H_ + q] * M2[q * H_ + i];
    W4h[i * H_ + t] = (_Float16)a;
}
__global__ void prepE1(const float* __restrict__ Wc, const float* __restrict__ wo,
                       const float* __restrict__ M2, const float* __restrict__ M3,
                       float* __restrict__ vf, _Float16* __restrict__ VV)
{   // v0=wo_h, v1=Mh*wo_h, v2=M2*wo_h, v3=M3*wo_h ; VV[16][128] rows>=4 zero
    const int i = threadIdx.x;   // 1 x 128
    float v0 = wo[25 + i], v1 = 0.f, v2 = 0.f, v3 = 0.f;
    for (int q = 0; q < H_; ++q) {
        float wh = wo[25 + q];
        v1 += Wc[(25 + i) * H_ + q] * wh;
        v2 += M2[i * H_ + q] * wh;
        v3 += M3[i * H_ + q] * wh;
    }
    vf[0 * H_ + i] = v0; vf[1 * H_ + i] = v1; vf[2 * H_ + i] = v2; vf[3 * H_ + i] = v3;
    VV[0 * H_ + i] = (_Float16)v0; VV[1 * H_ + i] = (_Float16)v1;
    VV[2 * H_ + i] = (_Float16)v2; VV[3 * H_ + i] = (_Float16)v3;
    for (int r = 4; r < 16; ++r) VV[r * H_ + i] = (_Float16)0.f;
}
__global__ void prepE2(const float* __restrict__ Wc, const float* __restrict__ wo,
                       const float* __restrict__ M2, const float* __restrict__ M3,
                       const float* __restrict__ vf,
                       _Float16* __restrict__ XWst, _Float16* __restrict__ OXT)
{   // blocks 0..127: XWst[k][i*32+p] = f16((Wxc * Mh^k)[p][i])  (transposed ok)
    // block 128: OXT[(j*16+r)*32+p] = (r>=j && r-j<4) ? w_{r-j}[p] : 0
    const int p = threadIdx.x;   // 32 threads
    if (blockIdx.x < 128) {
        const int i = blockIdx.x;
        float x0 = 0.f, x1 = 0.f, x2 = 0.f, x3 = 0.f;
        if (p < 26) {
            const int kp = (p < 25) ? p : 153;
            x0 = Wc[kp * H_ + i];
            for (int q = 0; q < H_; ++q) {
                float wx = Wc[kp * H_ + q];
                x1 += wx * Wc[(25 + q) * H_ + i];
                x2 += wx * M2[q * H_ + i];
                x3 += wx * M3[q * H_ + i];
            }
        }
        XWst[(0 * H_ + i) * 32 + p] = (_Float16)x0;
        XWst[(1 * H_ + i) * 32 + p] = (_Float16)x1;
        XWst[(2 * H_ + i) * 32 + p] = (_Float16)x2;
        XWst[(3 * H_ + i) * 32 + p] = (_Float16)x3;
    } else {
        float w0 = 0.f, w1 = 0.f, w2 = 0.f, w3 = 0.f;
        if (p < 26) {
            const int kp = (p < 25) ? p : 153;
            w0 = wo[kp];
            for (int q = 0; q < H_; ++q) {
                float wx = Wc[kp * H_ + q];
                w1 += wx * vf[0 * H_ + q];
                w2 += wx * vf[1 * H_ + q];
                w3 += wx * vf[2 * H_ + q];
            }
        }
        float wa[4] = {w0, w1, w2, w3};
        for (int j = 0; j < 4; ++j)
            for (int r = 0; r < 16; ++r)
                OXT[(j * 16 + r) * 32 + p] =
                    (r >= j && r - j < 4) ? (_Float16)wa[r - j] : (_Float16)0.f;
    }
}

// ---------------------------------------------------------------------------
// 1024 blocks x 64 thr (1 wave/SIMD). Wave owns a 16-row chain; 4-STEP batch:
// h_{s+4} = h_s*Mh^4 + sum_j xc_{s+j}*(Wxc*Mh^{3-j});  out_{s+j} via one
// shared out-tile (rows 0..3 = step projections, acco[0..3] on g==0 lanes).
// 72 MFMA / 4 steps. Tail (pk2+permlane) once per 4 steps. No LDS but costS.
// ---------------------------------------------------------------------------
__global__ __launch_bounds__(64, 1) void rnn_main(
    const float* __restrict__ x, const float* __restrict__ hidden,
    const float* __restrict__ cost, const _Float16* __restrict__ W4h,
    const _Float16* __restrict__ XWst, const _Float16* __restrict__ VV,
    const _Float16* __restrict__ OXT, float* __restrict__ outs,
    float* __restrict__ hfin)
{
    __shared__ float costS[136];

    const int t = threadIdx.x;
    const int c = t & 15, g = t >> 4;
    const int b  = blockIdx.x >> 6;
    const int r0 = (blockIdx.x & 63) << 4;

    // ---- weights into registers ----
    h8 w4f[8][4];                          // Mh^4 (transposed store): A[m][k]
#pragma unroll
    for (int it = 0; it < 8; ++it)
#pragma unroll
        for (int kb = 0; kb < 4; ++kb)
            w4f[it][kb] = *reinterpret_cast<const h8*>(
                &W4h[(it * 16 + c) * H_ + kb * 32 + g * 8]);
    h8 xw0f[8], xw1f[8], xw2f[8], xw3f[8]; // Wxc*Mh^k: A[m][p=g*8+u]
#pragma unroll
    for (int it = 0; it < 8; ++it) {
        xw0f[it] = *reinterpret_cast<const h8*>(&XWst[(0 * H_ + it * 16 + c) * 32 + g * 8]);
        xw1f[it] = *reinterpret_cast<const h8*>(&XWst[(1 * H_ + it * 16 + c) * 32 + g * 8]);
        xw2f[it] = *reinterpret_cast<const h8*>(&XWst[(2 * H_ + it * 16 + c) * 32 + g * 8]);
        xw3f[it] = *reinterpret_cast<const h8*>(&XWst[(3 * H_ + it * 16 + c) * 32 + g * 8]);
    }
    h8 ohf[4];                             // out-tile h-slabs (rows>=4 zero via VV)
#pragma unroll
    for (int kb = 0; kb < 4; ++kb)
        ohf[kb] = *reinterpret_cast<const h8*>(&VV[c * H_ + kb * 32 + g * 8]);
    h8 oxf0, oxf1, oxf2, oxf3;             // out-tile xc-slabs (patterns baked)
    oxf0 = *reinterpret_cast<const h8*>(&OXT[(0 * 16 + c) * 32 + g * 8]);
    oxf1 = *reinterpret_cast<const h8*>(&OXT[(1 * 16 + c) * 32 + g * 8]);
    oxf2 = *reinterpret_cast<const h8*>(&OXT[(2 * 16 + c) * 32 + g * 8]);
    oxf3 = *reinterpret_cast<const h8*>(&OXT[(3 * 16 + c) * 32 + g * 8]);

    // ---- per-block cost table ----
    costS[t]      = cost[b * S_ + t];
    costS[t + 64] = cost[b * S_ + t + 64];
    if (t < 8) costS[128 + t] = 0.f;

    // ---- h(0) -> bf0..3 (B-frag: lane (c,g) = h[row c][kb*32+g*8+u]) ----
    h8 bf0, bf1, bf2, bf3;
    {
        const float* hp = hidden + ((long)(b * R_ + r0 + c)) * H_;
        float4 v0, v1;
#define LDH(KB, DST)                                                            \
        v0 = *reinterpret_cast<const float4*>(hp + (KB) * 32 + g * 8);          \
        v1 = *reinterpret_cast<const float4*>(hp + (KB) * 32 + g * 8 + 4);      \
        DST = mk8(h2u(pk2(v0.x, v0.y)), h2u(pk2(v0.z, v0.w)),                   \
                  h2u(pk2(v1.x, v1.y)), h2u(pk2(v1.z, v1.w)));
        LDH(0, bf0) LDH(1, bf1) LDH(2, bf2) LDH(3, bf3)
#undef LDH
    }

    // ---- x pipeline: lane (c,g) loads its own B-frag slice ----
    const int xoff  = (g == 3) ? 21 : g * 8;     // g=3 reads x[21..24] (use .w)
    const int xoff2 = (g == 3) ? 0 : 4;
    const float* xlane = x + (((long)b * S_) * R_ + r0 + c) * KIN + xoff;

    float4 X0a, X0b, X1a, X1b, X2a, X2b, X3a, X3b;
#define XLD(S, VA, VB) {                                                        \
        const float* p_ = xlane + (long)(S) * (R_ * KIN);                       \
        VA = *reinterpret_cast<const float4*>(p_);                              \
        VB = *reinterpret_cast<const float4*>(p_ + xoff2); }
    XLD(0, X0a, X0b) XLD(1, X1a, X1b) XLD(2, X2a, X2b) XLD(3, X3a, X3b)

    auto mkbx = [&](float4 v0, float4 v1, float cs) -> h8 {
        h2 z{};
        h2 d0 = (g == 3) ? pk2(v0.w, cs) : pk2(v0.x, v0.y);
        h2 d1 = (g == 3) ? z : pk2(v0.z, v0.w);
        h2 d2 = (g == 3) ? z : pk2(v1.x, v1.y);
        h2 d3 = (g == 3) ? z : pk2(v1.z, v1.w);
        return mk8(h2u(d0), h2u(d1), h2u(d2), h2u(d3));
    };

    float4 cc = *reinterpret_cast<const float4*>(&costS[0]);
    h8 bx0 = mkbx(X0a, X0b, cc.x), bx1 = mkbx(X1a, X1b, cc.y);
    h8 bx2 = mkbx(X2a, X2b, cc.z), bx3 = mkbx(X3a, X3b, cc.w);

    const f4v fz = {0.f, 0.f, 0.f, 0.f};
    f4v acc[8], acco;

#define MM(AF, BV, CV) __builtin_amdgcn_mfma_f32_16x16x32_f16((AF), (BV), (CV), 0, 0, 0)
#define TAIL(AE, AO, DST) do {                                                  \
    unsigned A0 = h2u(pk2((AE)[0], (AE)[1]));                                   \
    unsigned A1 = h2u(pk2((AE)[2], (AE)[3]));                                   \
    unsigned B0 = h2u(pk2((AO)[0], (AO)[1]));                                   \
    unsigned B1 = h2u(pk2((AO)[2], (AO)[3]));                                   \
    auto r0_ = __builtin_amdgcn_permlane32_swap(A0, B0, false, false);          \
    auto q0_ = __builtin_amdgcn_permlane16_swap(r0_[0], r0_[1], false, false);  \
    auto r1_ = __builtin_amdgcn_permlane32_swap(A1, B1, false, false);          \
    auto q1_ = __builtin_amdgcn_permlane16_swap(r1_[0], r1_[1], false, false);  \
    DST = mk8(q0_[0], q1_[0], q0_[1], q1_[1]);                                  \
} while (0)

    for (int s4 = 0; s4 < S_; s4 += 4) {
        // issue next-iter x loads (wrap-clamped; landed by bottom-of-iter cvt)
        {
            const int sn = (s4 + 4) & (S_ - 1);
            XLD(sn,     X0a, X0b) XLD(sn + 1, X1a, X1b)
            XLD(sn + 2, X2a, X2b) XLD(sn + 3, X3a, X3b)
        }
        // ---- x-phase: 36 MFMA, zero dependence on bf (tail-overlap window) ----
        acco = MM(oxf0, bx0, fz);
#pragma unroll
        for (int it = 0; it < 8; ++it) acc[it] = MM(xw3f[it], bx0, fz);
        acco = MM(oxf1, bx1, acco);
#pragma unroll
        for (int it = 0; it < 8; ++it) acc[it] = MM(xw2f[it], bx1, acc[it]);
        acco = MM(oxf2, bx2, acco);
#pragma unroll
        for (int it = 0; it < 8; ++it) acc[it] = MM(xw1f[it], bx2, acc[it]);
        acco = MM(oxf3, bx3, acco);
#pragma unroll
        for (int it = 0; it < 8; ++it) acc[it] = MM(xw0f[it], bx3, acc[it]);
        // ---- h-phase: 36 MFMA ----
        acco = MM(ohf[0], bf0, acco);
#pragma unroll
        for (int it = 0; it < 8; ++it) acc[it] = MM(w4f[it][0], bf0, acc[it]);
        acco = MM(ohf[1], bf1, acco);
#pragma unroll
        for (int it = 0; it < 8; ++it) acc[it] = MM(w4f[it][1], bf1, acc[it]);
        acco = MM(ohf[2], bf2, acco);
#pragma unroll
        for (int it = 0; it < 8; ++it) acc[it] = MM(w4f[it][2], bf2, acc[it]);
        acco = MM(ohf[3], bf3, acco);
#pragma unroll
        for (int it = 0; it < 8; ++it) acc[it] = MM(w4f[it][3], bf3, acc[it]);

        // ---- outs: D rows 0..3 live in g==0 lanes, regs 0..3 ----
        if (g == 0) {
            float* op = outs + (long)(b * S_ + s4) * R_ + r0 + c;
            op[0]      = acco[0];
            op[R_]     = acco[1];
            op[2 * R_] = acco[2];
            op[3 * R_] = acco[3];
        }
        // ---- tail: h_{s+4} -> next bf (once per 4 steps) ----
        TAIL(acc[0], acc[1], bf0);
        TAIL(acc[2], acc[3], bf1);
        TAIL(acc[4], acc[5], bf2);
        TAIL(acc[6], acc[7], bf3);
        // ---- convert next iter's bx (loads issued at top of THIS iter) ----
        float4 ccn = *reinterpret_cast<const float4*>(&costS[s4 + 4]);  // pad-safe
        bx0 = mkbx(X0a, X0b, ccn.x);
        bx1 = mkbx(X1a, X1b, ccn.y);
        bx2 = mkbx(X2a, X2b, ccn.z);
        bx3 = mkbx(X3a, X3b, ccn.w);
    }
#undef TAIL
#undef MM
#undef XLD

    // ---- h_final = h_128 from last accumulators (D layout i = it*16+g*4+j) ----
#pragma unroll
    for (int it = 0; it < 8; ++it)
        *reinterpret_cast<f4v*>(
            &hfin[((long)(b * R_ + r0 + c)) * H_ + it * 16 + g * 4]) = acc[it];
}

// ---------------------------------------------------------------------------
extern "C" void kernel_launch(void* const* d_in, const int* in_sizes, int n_in,
                              void* d_out, int out_size, void* d_ws, size_t ws_size,
                              hipStream_t stream)
{
    const float* x      = (const float*)d_in[0];
    const float* hidden = (const float*)d_in[1];
    const float* cost   = (const float*)d_in[2];
    const float* Wo1    = (const float*)d_in[3];
    const float* Wo2    = (const float*)d_in[4];
    const float* Wh1    = (const float*)d_in[5];
    const float* Wh2    = (const float*)d_in[6];

    float* outs = (float*)d_out;                    // [B,S,R]
    float* hfin = outs + (long)B_ * S_ * R_;        // [B,R,H]

    // workspace layout
    char* wsb = (char*)d_ws;
    float*    Wc   = (float*)wsb;                       wsb += 154 * H_ * 4;
    float*    wo   = (float*)wsb;                       wsb += 160 * 4;
    float*    M2   = (float*)wsb;                       wsb += H_ * H_ * 4;
    float*    M3   = (float*)wsb;                       wsb += H_ * H_ * 4;
    float*    vf   = (float*)wsb;                       wsb += 4 * H_ * 4;
    _Float16* W4h  = (_Float16*)wsb;                    wsb += H_ * H_ * 2;
    _Float16* XWst = (_Float16*)wsb;                    wsb += 4 * H_ * 32 * 2;
    _Float16* VV   = (_Float16*)wsb;                    wsb += 16 * H_ * 2;
    _Float16* OXT  = (_Float16*)wsb;                    wsb += 4 * 16 * 32 * 2;

    prepA<<<155, 128, 0, stream>>>(Wh1, Wh2, Wo1, Wo2, Wc, wo);
    prepB<<<128, 128, 0, stream>>>(Wc, M2);
    prepC<<<128, 128, 0, stream>>>(Wc, M2, M3);
    prepD<<<128, 128, 0, stream>>>(M2, W4h);
    prepE1<<<1, 128, 0, stream>>>(Wc, wo, M2, M3, vf, VV);
    prepE2<<<129, 32, 0, stream>>>(Wc, wo, M2, M3, vf, XWst, OXT);
    rnn_main<<<1024, 64, 0, stream>>>(x, hidden, cost, W4h, XWst, VV, OXT, outs, hfin);
}

// Round 20
// 102.184 us; speedup vs baseline: 1.0605x; 1.0605x over previous
//
#include <hip/hip_runtime.h>

#define B_   16
#define S_   128
#define R_   1024
#define KIN  25
#define H_   128
#define MID  256

typedef _Float16 h8 __attribute__((ext_vector_type(8)));
typedef _Float16 h2 __attribute__((ext_vector_type(2)));
typedef float    f4v __attribute__((ext_vector_type(4)));

__device__ __forceinline__ h2 pk2(float a, float b) {
    auto r = __builtin_amdgcn_cvt_pkrtz(a, b);
    h2 o; o[0] = (_Float16)r[0]; o[1] = (_Float16)r[1]; return o;
}
__device__ __forceinline__ unsigned h2u(h2 v) {
    union { h2 h; unsigned u; } c; c.h = v; return c.u;
}
__device__ __forceinline__ h8 mk8(unsigned a, unsigned b, unsigned c, unsigned d) {
    union { h8 v; unsigned u[4]; } r; r.u[0] = a; r.u[1] = b; r.u[2] = c; r.u[3] = d;
    return r.v;
}

// ---------------------------------------------------------------------------
// prep chain (fp32 until final pack). Wc[k][j], k in ORIGINAL order:
// 0..24 = x, 25..152 = h, 153 = c.  Mh[i][j] = Wc[25+i][j] (h -> h map).
// A-fragment tables stored transposed: stored[i][k] = M[k][i].
// 4 launches: prepA -> prepB -> prepCD -> prepE. All inner loops unrolled x8.
// ---------------------------------------------------------------------------
__global__ void prepA(const float* __restrict__ Wh1, const float* __restrict__ Wh2,
                      const float* __restrict__ Wo1, const float* __restrict__ Wo2,
                      float* __restrict__ Wc, float* __restrict__ wo)
{
    const int k = blockIdx.x, t = threadIdx.x;    // 155 x 128
    if (k < 154) {
        float a = 0.f;
#pragma unroll 8
        for (int m = 0; m < MID; ++m) a += Wh1[k * MID + m] * Wh2[m * H_ + t];
        Wc[k * H_ + t] = a;
    } else {
#pragma unroll
        for (int r = 0; r < 2; ++r) {
            int kk = t + r * 128;
            if (kk < 154) {
                float a = 0.f;
#pragma unroll 8
                for (int m = 0; m < MID; ++m) a += Wo1[kk * MID + m] * Wo2[m];
                wo[kk] = a;
            }
        }
    }
}
__global__ void prepB(const float* __restrict__ Wc, float* __restrict__ M2)
{   // M2 = Mh^2 (actual orientation)
    const int i = blockIdx.x, t = threadIdx.x;
    float a = 0.f;
#pragma unroll 8
    for (int q = 0; q < H_; ++q) a += Wc[(25 + i) * H_ + q] * Wc[(25 + q) * H_ + t];
    M2[i * H_ + t] = a;
}
__global__ void prepCD(const float* __restrict__ Wc, const float* __restrict__ M2,
                       float* __restrict__ M3, _Float16* __restrict__ W4h)
{   // M3 = M2*Mh (actual); W4h[i][t] = Mh^4[t][i] (TRANSPOSED for A-frag)
    const int i = blockIdx.x, t = threadIdx.x;
    float a3 = 0.f, a4 = 0.f;
#pragma unroll 8
    for (int q = 0; q < H_; ++q) {
        a3 += M2[i * H_ + q] * Wc[(25 + q) * H_ + t];
        a4 += M2[t * H_ + q] * M2[q * H_ + i];
    }
    M3[i * H_ + t] = a3;
    W4h[i * H_ + t] = (_Float16)a4;
}
__global__ void prepE(const float* __restrict__ Wc, const float* __restrict__ wo,
                      const float* __restrict__ M2, const float* __restrict__ M3,
                      _Float16* __restrict__ XWst, _Float16* __restrict__ VV,
                      _Float16* __restrict__ OXT)
{   // blocks 0..127 (t<32): XWst[k][i*32+p] = f16((Wxc*Mh^k)[p][i])
    // block 128: VV rows (v_k = Mh^k * wo_h) + OXT patterns (vf via LDS)
    const int t = threadIdx.x;   // 128 threads
    if (blockIdx.x < 128) {
        if (t < 32) {
            const int i = blockIdx.x, p = t;
            float x0 = 0.f, x1 = 0.f, x2 = 0.f, x3 = 0.f;
            if (p < 26) {
                const int kp = (p < 25) ? p : 153;
                x0 = Wc[kp * H_ + i];
#pragma unroll 8
                for (int q = 0; q < H_; ++q) {
                    float wx = Wc[kp * H_ + q];
                    x1 += wx * Wc[(25 + q) * H_ + i];
                    x2 += wx * M2[q * H_ + i];
                    x3 += wx * M3[q * H_ + i];
                }
            }
            XWst[(0 * H_ + i) * 32 + p] = (_Float16)x0;
            XWst[(1 * H_ + i) * 32 + p] = (_Float16)x1;
            XWst[(2 * H_ + i) * 32 + p] = (_Float16)x2;
            XWst[(3 * H_ + i) * 32 + p] = (_Float16)x3;
        }
    } else {
        __shared__ float vfs[3][H_];
        const int i = t;
        float v0 = wo[25 + i], v1 = 0.f, v2 = 0.f, v3 = 0.f;
#pragma unroll 8
        for (int q = 0; q < H_; ++q) {
            float wh = wo[25 + q];
            v1 += Wc[(25 + i) * H_ + q] * wh;
            v2 += M2[i * H_ + q] * wh;
            v3 += M3[i * H_ + q] * wh;
        }
        VV[0 * H_ + i] = (_Float16)v0; VV[1 * H_ + i] = (_Float16)v1;
        VV[2 * H_ + i] = (_Float16)v2; VV[3 * H_ + i] = (_Float16)v3;
#pragma unroll
        for (int r = 4; r < 16; ++r) VV[r * H_ + i] = (_Float16)0.f;
        vfs[0][i] = v0; vfs[1][i] = v1; vfs[2][i] = v2;
        __syncthreads();
        if (t < 32) {
            const int p = t;
            float w0 = 0.f, w1 = 0.f, w2 = 0.f, w3 = 0.f;
            if (p < 26) {
                const int kp = (p < 25) ? p : 153;
                w0 = wo[kp];
#pragma unroll 8
                for (int q = 0; q < H_; ++q) {
                    float wx = Wc[kp * H_ + q];
                    w1 += wx * vfs[0][q];
                    w2 += wx * vfs[1][q];
                    w3 += wx * vfs[2][q];
                }
            }
            float wa[4] = {w0, w1, w2, w3};
            for (int j = 0; j < 4; ++j)
                for (int r = 0; r < 16; ++r)
                    OXT[(j * 16 + r) * 32 + p] =
                        (r >= j && r - j < 4) ? (_Float16)wa[r - j] : (_Float16)0.f;
        }
    }
}

// ---------------------------------------------------------------------------
// 1024 blocks x 64 thr (1 wave/SIMD). Wave owns a 16-row chain; 4-STEP batch:
// h_{s+4} = h_s*Mh^4 + sum_j xc_{s+j}*(Wxc*Mh^{3-j});  out_{s+j} via one
// shared out-tile (rows 0..3 = step projections, acco[0..3] on g==0 lanes).
// 72 MFMA / 4 steps. Tail (pk2+permlane) once per 4 steps. (= R19, passing)
// ---------------------------------------------------------------------------
__global__ __launch_bounds__(64, 1) void rnn_main(
    const float* __restrict__ x, const float* __restrict__ hidden,
    const float* __restrict__ cost, const _Float16* __restrict__ W4h,
    const _Float16* __restrict__ XWst, const _Float16* __restrict__ VV,
    const _Float16* __restrict__ OXT, float* __restrict__ outs,
    float* __restrict__ hfin)
{
    __shared__ float costS[136];

    const int t = threadIdx.x;
    const int c = t & 15, g = t >> 4;
    const int b  = blockIdx.x >> 6;
    const int r0 = (blockIdx.x & 63) << 4;

    // ---- weights into registers ----
    h8 w4f[8][4];                          // Mh^4 (transposed store): A[m][k]
#pragma unroll
    for (int it = 0; it < 8; ++it)
#pragma unroll
        for (int kb = 0; kb < 4; ++kb)
            w4f[it][kb] = *reinterpret_cast<const h8*>(
                &W4h[(it * 16 + c) * H_ + kb * 32 + g * 8]);
    h8 xw0f[8], xw1f[8], xw2f[8], xw3f[8]; // Wxc*Mh^k: A[m][p=g*8+u]
#pragma unroll
    for (int it = 0; it < 8; ++it) {
        xw0f[it] = *reinterpret_cast<const h8*>(&XWst[(0 * H_ + it * 16 + c) * 32 + g * 8]);
        xw1f[it] = *reinterpret_cast<const h8*>(&XWst[(1 * H_ + it * 16 + c) * 32 + g * 8]);
        xw2f[it] = *reinterpret_cast<const h8*>(&XWst[(2 * H_ + it * 16 + c) * 32 + g * 8]);
        xw3f[it] = *reinterpret_cast<const h8*>(&XWst[(3 * H_ + it * 16 + c) * 32 + g * 8]);
    }
    h8 ohf[4];                             // out-tile h-slabs (rows>=4 zero via VV)
#pragma unroll
    for (int kb = 0; kb < 4; ++kb)
        ohf[kb] = *reinterpret_cast<const h8*>(&VV[c * H_ + kb * 32 + g * 8]);
    h8 oxf0, oxf1, oxf2, oxf3;             // out-tile xc-slabs (patterns baked)
    oxf0 = *reinterpret_cast<const h8*>(&OXT[(0 * 16 + c) * 32 + g * 8]);
    oxf1 = *reinterpret_cast<const h8*>(&OXT[(1 * 16 + c) * 32 + g * 8]);
    oxf2 = *reinterpret_cast<const h8*>(&OXT[(2 * 16 + c) * 32 + g * 8]);
    oxf3 = *reinterpret_cast<const h8*>(&OXT[(3 * 16 + c) * 32 + g * 8]);

    // ---- per-block cost table ----
    costS[t]      = cost[b * S_ + t];
    costS[t + 64] = cost[b * S_ + t + 64];
    if (t < 8) costS[128 + t] = 0.f;

    // ---- h(0) -> bf0..3 (B-frag: lane (c,g) = h[row c][kb*32+g*8+u]) ----
    h8 bf0, bf1, bf2, bf3;
    {
        const float* hp = hidden + ((long)(b * R_ + r0 + c)) * H_;
        float4 v0, v1;
#define LDH(KB, DST)                                                            \
        v0 = *reinterpret_cast<const float4*>(hp + (KB) * 32 + g * 8);          \
        v1 = *reinterpret_cast<const float4*>(hp + (KB) * 32 + g * 8 + 4);      \
        DST = mk8(h2u(pk2(v0.x, v0.y)), h2u(pk2(v0.z, v0.w)),                   \
                  h2u(pk2(v1.x, v1.y)), h2u(pk2(v1.z, v1.w)));
        LDH(0, bf0) LDH(1, bf1) LDH(2, bf2) LDH(3, bf3)
#undef LDH
    }

    // ---- x pipeline: lane (c,g) loads its own B-frag slice ----
    const int xoff  = (g == 3) ? 21 : g * 8;     // g=3 reads x[21..24] (use .w)
    const int xoff2 = (g == 3) ? 0 : 4;
    const float* xlane = x + (((long)b * S_) * R_ + r0 + c) * KIN + xoff;

    float4 X0a, X0b, X1a, X1b, X2a, X2b, X3a, X3b;
#define XLD(S, VA, VB) {                                                        \
        const float* p_ = xlane + (long)(S) * (R_ * KIN);                       \
        VA = *reinterpret_cast<const float4*>(p_);                              \
        VB = *reinterpret_cast<const float4*>(p_ + xoff2); }
    XLD(0, X0a, X0b) XLD(1, X1a, X1b) XLD(2, X2a, X2b) XLD(3, X3a, X3b)

    auto mkbx = [&](float4 v0, float4 v1, float cs) -> h8 {
        h2 z{};
        h2 d0 = (g == 3) ? pk2(v0.w, cs) : pk2(v0.x, v0.y);
        h2 d1 = (g == 3) ? z : pk2(v0.z, v0.w);
        h2 d2 = (g == 3) ? z : pk2(v1.x, v1.y);
        h2 d3 = (g == 3) ? z : pk2(v1.z, v1.w);
        return mk8(h2u(d0), h2u(d1), h2u(d2), h2u(d3));
    };

    float4 cc = *reinterpret_cast<const float4*>(&costS[0]);
    h8 bx0 = mkbx(X0a, X0b, cc.x), bx1 = mkbx(X1a, X1b, cc.y);
    h8 bx2 = mkbx(X2a, X2b, cc.z), bx3 = mkbx(X3a, X3b, cc.w);

    const f4v fz = {0.f, 0.f, 0.f, 0.f};
    f4v acc[8], acco;

#define MM(AF, BV, CV) __builtin_amdgcn_mfma_f32_16x16x32_f16((AF), (BV), (CV), 0, 0, 0)
#define TAIL(AE, AO, DST) do {                                                  \
    unsigned A0 = h2u(pk2((AE)[0], (AE)[1]));                                   \
    unsigned A1 = h2u(pk2((AE)[2], (AE)[3]));                                   \
    unsigned B0 = h2u(pk2((AO)[0], (AO)[1]));                                   \
    unsigned B1 = h2u(pk2((AO)[2], (AO)[3]));                                   \
    auto r0_ = __builtin_amdgcn_permlane32_swap(A0, B0, false, false);          \
    auto q0_ = __builtin_amdgcn_permlane16_swap(r0_[0], r0_[1], false, false);  \
    auto r1_ = __builtin_amdgcn_permlane32_swap(A1, B1, false, false);          \
    auto q1_ = __builtin_amdgcn_permlane16_swap(r1_[0], r1_[1], false, false);  \
    DST = mk8(q0_[0], q1_[0], q0_[1], q1_[1]);                                  \
} while (0)

    for (int s4 = 0; s4 < S_; s4 += 4) {
        // issue next-iter x loads (wrap-clamped; landed by bottom-of-iter cvt)
        {
            const int sn = (s4 + 4) & (S_ - 1);
            XLD(sn,     X0a, X0b) XLD(sn + 1, X1a, X1b)
            XLD(sn + 2, X2a, X2b) XLD(sn + 3, X3a, X3b)
        }
        // ---- x-phase: 36 MFMA, zero dependence on bf (tail-overlap window) ----
        acco = MM(oxf0, bx0, fz);
#pragma unroll
        for (int it = 0; it < 8; ++it) acc[it] = MM(xw3f[it], bx0, fz);
        acco = MM(oxf1, bx1, acco);
#pragma unroll
        for (int it = 0; it < 8; ++it) acc[it] = MM(xw2f[it], bx1, acc[it]);
        acco = MM(oxf2, bx2, acco);
#pragma unroll
        for (int it = 0; it < 8; ++it) acc[it] = MM(xw1f[it], bx2, acc[it]);
        acco = MM(oxf3, bx3, acco);
#pragma unroll
        for (int it = 0; it < 8; ++it) acc[it] = MM(xw0f[it], bx3, acc[it]);
        // ---- h-phase: 36 MFMA ----
        acco = MM(ohf[0], bf0, acco);
#pragma unroll
        for (int it = 0; it < 8; ++it) acc[it] = MM(w4f[it][0], bf0, acc[it]);
        acco = MM(ohf[1], bf1, acco);
#pragma unroll
        for (int it = 0; it < 8; ++it) acc[it] = MM(w4f[it][1], bf1, acc[it]);
        acco = MM(ohf[2], bf2, acco);
#pragma unroll
        for (int it = 0; it < 8; ++it) acc[it] = MM(w4f[it][2], bf2, acc[it]);
        acco = MM(ohf[3], bf3, acco);
#pragma unroll
        for (int it = 0; it < 8; ++it) acc[it] = MM(w4f[it][3], bf3, acc[it]);

        // ---- outs: D rows 0..3 live in g==0 lanes, regs 0..3 ----
        if (g == 0) {
            float* op = outs + (long)(b * S_ + s4) * R_ + r0 + c;
            op[0]      = acco[0];
            op[R_]     = acco[1];
            op[2 * R_] = acco[2];
            op[3 * R_] = acco[3];
        }
        // ---- tail: h_{s+4} -> next bf (once per 4 steps) ----
        TAIL(acc[0], acc[1], bf0);
        TAIL(acc[2], acc[3], bf1);
        TAIL(acc[4], acc[5], bf2);
        TAIL(acc[6], acc[7], bf3);
        // ---- convert next iter's bx (loads issued at top of THIS iter) ----
        float4 ccn = *reinterpret_cast<const float4*>(&costS[s4 + 4]);  // pad-safe
        bx0 = mkbx(X0a, X0b, ccn.x);
        bx1 = mkbx(X1a, X1b, ccn.y);
        bx2 = mkbx(X2a, X2b, ccn.z);
        bx3 = mkbx(X3a, X3b, ccn.w);
    }
#undef TAIL
#undef MM
#undef XLD

    // ---- h_final = h_128 from last accumulators (D layout i = it*16+g*4+j) ----
#pragma unroll
    for (int it = 0; it < 8; ++it)
        *reinterpret_cast<f4v*>(
            &hfin[((long)(b * R_ + r0 + c)) * H_ + it * 16 + g * 4]) = acc[it];
}

// ---------------------------------------------------------------------------
extern "C" void kernel_launch(void* const* d_in, const int* in_sizes, int n_in,
                              void* d_out, int out_size, void* d_ws, size_t ws_size,
                              hipStream_t stream)
{
    const float* x      = (const float*)d_in[0];
    const float* hidden = (const float*)d_in[1];
    const float* cost   = (const float*)d_in[2];
    const float* Wo1    = (const float*)d_in[3];
    const float* Wo2    = (const float*)d_in[4];
    const float* Wh1    = (const float*)d_in[5];
    const float* Wh2    = (const float*)d_in[6];

    float* outs = (float*)d_out;                    // [B,S,R]
    float* hfin = outs + (long)B_ * S_ * R_;        // [B,R,H]

    // workspace layout
    char* wsb = (char*)d_ws;
    float*    Wc   = (float*)wsb;                       wsb += 154 * H_ * 4;
    float*    wo   = (float*)wsb;                       wsb += 160 * 4;
    float*    M2   = (float*)wsb;                       wsb += H_ * H_ * 4;
    float*    M3   = (float*)wsb;                       wsb += H_ * H_ * 4;
    _Float16* W4h  = (_Float16*)wsb;                    wsb += H_ * H_ * 2;
    _Float16* XWst = (_Float16*)wsb;                    wsb += 4 * H_ * 32 * 2;
    _Float16* VV   = (_Float16*)wsb;                    wsb += 16 * H_ * 2;
    _Float16* OXT  = (_Float16*)wsb;                    wsb += 4 * 16 * 32 * 2;

    prepA<<<155, 128, 0, stream>>>(Wh1, Wh2, Wo1, Wo2, Wc, wo);
    prepB<<<128, 128, 0, stream>>>(Wc, M2);
    prepCD<<<128, 128, 0, stream>>>(Wc, M2, M3, W4h);
    prepE<<<129, 128, 0, stream>>>(Wc, wo, M2, M3, XWst, VV, OXT);
    rnn_main<<<1024, 64, 0, stream>>>(x, hidden, cost, W4h, XWst, VV, OXT, outs, hfin);
}